// Round 4
// baseline (615.817 us; speedup 1.0000x reference)
//
#include <hip/hip_runtime.h>
#include <hip/hip_bf16.h>

// Affine collapse: B(v)=v*M+c with M = fc1_W^T @ fc2_W^T, T = I-M.
//   inv_total = x*(S*M) + c*S,  S = I+T+T^2+T^3+T^4 ;  nxt = x - inv_total
//   out_i = x*Bout_i + f_i,  Bout_i = T^{i-1}*(M*compW_i^T)
// One main GEMM [8192 x 6144 x 1024] computes invtot + all five out_i.
// Loss: c[n,j] = sign(out[n,j]) * S_n/(32*n2_n)  (exact for |ov|>~1e-11, c=0 at ov==0),
// so only int8 signs + per-row S,Q leave the main GEMM. loss[a,b] = Dtot[b] (rank-1).

#define NR 8192
#define DD 1024
#define HH 4096
#define NL 5
#define MSZ (DD * DD)

using bf16 = __hip_bfloat16;
typedef __attribute__((ext_vector_type(8))) short bf16x8;
typedef __attribute__((ext_vector_type(4))) float f32x4;

// ---------------- fused prep: all conversions + cvec + zeroing ----------------
__global__ void prep_kernel(const float* __restrict__ x, const float* __restrict__ fc2_W,
                            const float* __restrict__ comp_W, const float* __restrict__ fc1_W,
                            const float* __restrict__ fc1_b, const float* __restrict__ fc2_b,
                            bf16* __restrict__ x_bf, bf16* __restrict__ fc2_bf,
                            bf16* __restrict__ compW_bf, bf16* __restrict__ fc1T_bf,
                            float* __restrict__ cvec, float* __restrict__ stats, int nstats) {
  const int b = blockIdx.x;
  union U { bf16 h[4]; uint2 u; };
  auto cvt_range = [&](const float* in, bf16* out, int n4, int b0, int nb) {
    int i = (b - b0) * 256 + threadIdx.x;
    int stride = nb * 256;
    for (; i < n4; i += stride) {
      float4 v = ((const float4*)in)[i];
      U u;
      u.h[0] = __float2bfloat16(v.x); u.h[1] = __float2bfloat16(v.y);
      u.h[2] = __float2bfloat16(v.z); u.h[3] = __float2bfloat16(v.w);
      ((uint2*)out)[i] = u.u;
    }
  };
  if (b < 1024) {                    // x cvt
    cvt_range(x, x_bf, NR * DD / 4, 0, 1024);
  } else if (b < 1536) {             // fc2 cvt
    cvt_range(fc2_W, fc2_bf, DD * HH / 4, 1024, 512);
  } else if (b < 2048) {             // compW cvt
    cvt_range(comp_W, compW_bf, NL * MSZ / 4, 1536, 512);
  } else if (b < 3072) {             // fc1 transpose+cvt
    __shared__ bf16 tile[64][74];
    int b2 = b - 2048;
    int c0 = (b2 & 15) * 64;
    int r0 = (b2 >> 4) * 64;
    int col = threadIdx.x & 63;
    int row4 = threadIdx.x >> 6;
    #pragma unroll
    for (int j = 0; j < 16; ++j) {
      int r = row4 * 16 + j;
      tile[r][col] = __float2bfloat16(fc1_W[(size_t)(r0 + r) * DD + c0 + col]);
    }
    __syncthreads();
    #pragma unroll
    for (int j = 0; j < 16; ++j) {
      int r = row4 * 16 + j;
      fc1T_bf[(size_t)(c0 + r) * HH + r0 + col] = tile[col][r];
    }
  } else if (b < 4096) {             // cvec: c[j] = fc1_b . fc2_W[j,:] + fc2_b[j]
    int j = b - 3072;
    float s = 0.f;
    for (int k = threadIdx.x; k < HH; k += 256) s += fc1_b[k] * fc2_W[(size_t)j * HH + k];
    for (int o = 32; o; o >>= 1) s += __shfl_down(s, o);
    __shared__ float red[4];
    if ((threadIdx.x & 63) == 0) red[threadIdx.x >> 6] = s;
    __syncthreads();
    if (threadIdx.x == 0) cvec[j] = red[0] + red[1] + red[2] + red[3] + fc2_b[j];
  } else {                           // zero stats
    int i = (b - 4096) * 256 + threadIdx.x;
    if (i < nstats) stats[i] = 0.f;
  }
}

// sum 4 split-K fp32 partials -> M (bf16, normal+transposed) and T=I-M (normal+transposed)
__global__ void mbuild_kernel(const float* __restrict__ Cp,
                              bf16* __restrict__ M, bf16* __restrict__ Mt,
                              bf16* __restrict__ T, bf16* __restrict__ Tt) {
  __shared__ float tile[64][65];
  int n0 = blockIdx.x * 64, m0 = blockIdx.y * 64;
  int tn = threadIdx.x & 63, tm4 = threadIdx.x >> 6;
  #pragma unroll
  for (int j = 0; j < 16; ++j) {
    int m = tm4 * 16 + j;
    size_t idx = (size_t)(m0 + m) * DD + n0 + tn;
    float v = Cp[idx] + Cp[MSZ + idx] + Cp[2 * MSZ + idx] + Cp[3 * MSZ + idx];
    tile[m][tn] = v;
    float d = ((m0 + m) == (n0 + tn)) ? 1.f : 0.f;
    M[idx] = __float2bfloat16(v);
    T[idx] = __float2bfloat16(d - v);
  }
  __syncthreads();
  #pragma unroll
  for (int j = 0; j < 16; ++j) {
    int r = tm4 * 16 + j;
    float v = tile[tn][r];
    size_t idx = (size_t)(n0 + r) * DD + m0 + tn;
    float d = ((n0 + r) == (m0 + tn)) ? 1.f : 0.f;
    Mt[idx] = __float2bfloat16(v);
    Tt[idx] = __float2bfloat16(d - v);
  }
}

// S = I + T + T2 + T3 + T4  (Pw = [T,T2,T3,T4] contiguous)
__global__ void sbuild_kernel(const bf16* __restrict__ Pw, bf16* __restrict__ S) {
  int idx = blockIdx.x * 256 + threadIdx.x;
  int m = idx >> 10, n = idx & (DD - 1);
  float v = (m == n) ? 1.f : 0.f;
  v += __bfloat162float(Pw[idx]) + __bfloat162float(Pw[MSZ + idx])
     + __bfloat162float(Pw[2 * MSZ + idx]) + __bfloat162float(Pw[3 * MSZ + idx]);
  S[idx] = __float2bfloat16(v);
}

// e_{z+2} = c . T^{z+1}  for z=0..3, from transposed powers Ttb=[Tt,T2t,T3t,T4t]
__global__ void vecmat4_kernel(const float* __restrict__ v, const bf16* __restrict__ Ttb,
                               float* __restrict__ ebuf) {
  int z = blockIdx.y, j = blockIdx.x;
  const bf16* row = Ttb + (size_t)z * MSZ + (size_t)j * DD;
  float s = 0.f;
  for (int k = threadIdx.x; k < DD; k += 256) s += v[k] * __bfloat162float(row[k]);
  for (int o = 32; o; o >>= 1) s += __shfl_down(s, o);
  __shared__ float red[4];
  if ((threadIdx.x & 63) == 0) red[threadIdx.x >> 6] = s;
  __syncthreads();
  if (threadIdx.x == 0) ebuf[(size_t)z * DD + j] = red[0] + red[1] + red[2] + red[3];
}

// biasall[0..1023] = c+e2+e3+e4+e5 ; biasall[z*1024+j] = e_z . compW_z[j,:] + b_z (z=1..5)
__global__ void biasall_kernel(const float* __restrict__ cvec, const float* __restrict__ ebuf,
                               const bf16* __restrict__ compW_bf, const float* __restrict__ comp_b,
                               float* __restrict__ biasall) {
  int z = blockIdx.y, j = blockIdx.x;
  if (z == 0) {
    if (threadIdx.x == 0)
      biasall[j] = cvec[j] + ebuf[j] + ebuf[DD + j] + ebuf[2 * DD + j] + ebuf[3 * DD + j];
    return;
  }
  int i = z - 1;
  const float* e = (i == 0) ? cvec : ebuf + (size_t)(i - 1) * DD;
  const bf16* wr = compW_bf + (size_t)i * MSZ + (size_t)j * DD;
  float s = 0.f;
  for (int k = threadIdx.x; k < DD; k += 256) s += e[k] * __bfloat162float(wr[k]);
  for (int o = 32; o; o >>= 1) s += __shfl_down(s, o);
  __shared__ float red[4];
  if ((threadIdx.x & 63) == 0) red[threadIdx.x >> 6] = s;
  __syncthreads();
  if (threadIdx.x == 0)
    biasall[(size_t)z * DD + j] = red[0] + red[1] + red[2] + red[3] + comp_b[(size_t)i * DD + j];
}

// ---------------- async GEMM core: C[m,n] = sum_k A[m,k]*B[n,k] ----------------
// BM=BN=128, BK=64; global_load_lds width=16 direct-to-LDS; XOR-swizzled unpadded LDS
// (phys_chunk = logical_chunk ^ (row&7); 2-way bank aliasing only — free per m136).

__device__ __forceinline__ void async16(const bf16* g, bf16* l) {
  __builtin_amdgcn_global_load_lds(
      (const __attribute__((address_space(1))) void*)g,
      (__attribute__((address_space(3))) void*)l, 16, 0, 0);
}

__device__ __forceinline__ void gemm_core_async(
    const bf16* __restrict__ A, const bf16* __restrict__ B,
    int kBeg, int kEnd, int lda, int ldb, int bm, int bn,
    bf16* As, bf16* Bs, f32x4 acc[4][4])
{
  const int tid  = threadIdx.x;
  const int lane = tid & 63;
  const int wave = tid >> 6;
  const int wm = (wave & 1) * 64;
  const int wn = (wave >> 1) * 64;
  const int lr = lane >> 3;
  const int lcol = ((lane & 7) ^ lr) * 8;
  const bf16* gA = A + (size_t)(bm + wave * 32 + lr) * lda + lcol;
  const bf16* gB = B + (size_t)(bn + wave * 32 + lr) * ldb + lcol;
  bf16* lA = As + wave * 32 * 64;
  bf16* lB = Bs + wave * 32 * 64;

  for (int k0 = kBeg; k0 < kEnd; k0 += 64) {
    #pragma unroll
    for (int it = 0; it < 4; ++it) {
      async16(gA + (size_t)(it * 8) * lda + k0, lA + it * 8 * 64);
      async16(gB + (size_t)(it * 8) * ldb + k0, lB + it * 8 * 64);
    }
    __syncthreads();
    #pragma unroll
    for (int ks = 0; ks < 2; ++ks) {
      bf16x8 av[4], bv[4];
      #pragma unroll
      for (int i = 0; i < 4; ++i) {
        const int rr = i * 16 + (lane & 15);
        const int cc = ((ks * 4 + (lane >> 4)) ^ (lane & 7)) * 8;
        av[i] = *(const bf16x8*)(As + (wm + rr) * 64 + cc);
        bv[i] = *(const bf16x8*)(Bs + (wn + rr) * 64 + cc);
      }
      #pragma unroll
      for (int i = 0; i < 4; ++i)
        #pragma unroll
        for (int j = 0; j < 4; ++j)
          acc[i][j] = __builtin_amdgcn_mfma_f32_16x16x32_bf16(av[i], bv[j], acc[i][j], 0, 0, 0);
    }
    __syncthreads();
  }
}

#define GEMM_PROLOGUE \
  alignas(16) __shared__ bf16 As[128 * 64]; \
  alignas(16) __shared__ bf16 Bs[128 * 64]; \
  f32x4 acc[4][4] = {}; \
  const int lane = threadIdx.x & 63; \
  const int wm = ((threadIdx.x >> 6) & 1) * 64; \
  const int wn = ((threadIdx.x >> 6) >> 1) * 64;

// split-K partial GEMM for M = fc1T * fc2 (K=4096 in 4 chunks), fp32 partials
__global__ __launch_bounds__(256, 4)
void gemm_splitk(const bf16* __restrict__ A, const bf16* __restrict__ B, float* __restrict__ Cp) {
  GEMM_PROLOGUE
  const int bm = blockIdx.y * 128, bn = blockIdx.x * 128;
  const int kb = blockIdx.z * (HH / 4);
  gemm_core_async(A, B, kb, kb + HH / 4, HH, HH, bm, bn, As, Bs, acc);
  float* C = Cp + (size_t)blockIdx.z * MSZ;
  #pragma unroll
  for (int i = 0; i < 4; ++i)
    #pragma unroll
    for (int j = 0; j < 4; ++j) {
      const int col = bn + wn + j * 16 + (lane & 15);
      #pragma unroll
      for (int r = 0; r < 4; ++r) {
        const int row = bm + wm + i * 16 + (lane >> 4) * 4 + r;
        C[(size_t)row * DD + col] = acc[i][j][r];
      }
    }
}

// batch of 6: z=0..4: G_{z+1}^T = compW_z . M^T (z=0 -> Bbig+MSZ = Bout1^T, else Gt[z-1]);
// z=5: T2 = T.T dual-written (normal -> Pw+MSZ, transposed -> Ttb+MSZ)
__global__ __launch_bounds__(256, 4)
void gemm_pre1(const bf16* __restrict__ compW_bf, const bf16* __restrict__ M_bf,
               const bf16* __restrict__ T, const bf16* __restrict__ Tt,
               bf16* __restrict__ Bbig, bf16* __restrict__ Gt,
               bf16* __restrict__ T2n, bf16* __restrict__ T2t) {
  GEMM_PROLOGUE
  const int z = blockIdx.z;
  const bf16* A = (z < 5) ? compW_bf + (size_t)z * MSZ : T;
  const bf16* B = (z < 5) ? M_bf : Tt;
  const int bm = blockIdx.y * 128, bn = blockIdx.x * 128;
  gemm_core_async(A, B, 0, DD, DD, DD, bm, bn, As, Bs, acc);
  if (z < 5) {
    bf16* C = (z == 0) ? Bbig : Gt + (size_t)(z - 1) * MSZ;
    #pragma unroll
    for (int i = 0; i < 4; ++i)
      #pragma unroll
      for (int j = 0; j < 4; ++j) {
        const int col = bn + wn + j * 16 + (lane & 15);
        #pragma unroll
        for (int r = 0; r < 4; ++r) {
          const int row = bm + wm + i * 16 + (lane >> 4) * 4 + r;
          C[(size_t)row * DD + col] = __float2bfloat16(acc[i][j][r]);
        }
      }
  } else {
    #pragma unroll
    for (int i = 0; i < 4; ++i)
      #pragma unroll
      for (int j = 0; j < 4; ++j) {
        const int col = bn + wn + j * 16 + (lane & 15);
        const int row0 = bm + wm + i * 16 + (lane >> 4) * 4;
        union { bf16 h[4]; uint2 u; } pk;
        #pragma unroll
        for (int r = 0; r < 4; ++r) {
          bf16 v = __float2bfloat16(acc[i][j][r]);
          pk.h[r] = v;
          T2n[(size_t)(row0 + r) * DD + col] = v;
        }
        *(uint2*)(&T2t[(size_t)col * DD + row0]) = pk.u;
      }
  }
}

// batch of 2 dual: z=0: T3 = T2.T ; z=1: T4 = T2.T2 ; write normal + transposed
__global__ __launch_bounds__(256, 4)
void gemm_pre2(const bf16* __restrict__ T2, const bf16* __restrict__ Ttb,
               bf16* __restrict__ Pw, bf16* __restrict__ Ttb_out) {
  GEMM_PROLOGUE
  const int z = blockIdx.z;
  const bf16* B = Ttb + (size_t)z * MSZ;          // Tt or T2t
  bf16* Cn = Pw + (size_t)(2 + z) * MSZ;
  bf16* Ct = Ttb_out + (size_t)(2 + z) * MSZ;
  const int bm = blockIdx.y * 128, bn = blockIdx.x * 128;
  gemm_core_async(T2, B, 0, DD, DD, DD, bm, bn, As, Bs, acc);
  #pragma unroll
  for (int i = 0; i < 4; ++i)
    #pragma unroll
    for (int j = 0; j < 4; ++j) {
      const int col = bn + wn + j * 16 + (lane & 15);
      const int row0 = bm + wm + i * 16 + (lane >> 4) * 4;
      union { bf16 h[4]; uint2 u; } pk;
      #pragma unroll
      for (int r = 0; r < 4; ++r) {
        bf16 v = __float2bfloat16(acc[i][j][r]);
        pk.h[r] = v;
        Cn[(size_t)(row0 + r) * DD + col] = v;
      }
      *(uint2*)(&Ct[(size_t)col * DD + row0]) = pk.u;
    }
}

// final batch: z=0..3: Bout_{z+2}^T = G_{z+2}^T . (T^{z+1})^T ; z=4: (S*M)^T = Mt . S^T
__global__ __launch_bounds__(256, 4)
void gemm_final(const bf16* __restrict__ Gt, const bf16* __restrict__ Pw,
                const bf16* __restrict__ Mt, const bf16* __restrict__ S_bf,
                bf16* __restrict__ Bbig) {
  GEMM_PROLOGUE
  const int z = blockIdx.z;
  const bf16* A; const bf16* B; bf16* C;
  if (z < 4) { A = Gt + (size_t)z * MSZ; B = Pw + (size_t)z * MSZ; C = Bbig + (size_t)(2 + z) * MSZ; }
  else       { A = Mt; B = S_bf; C = Bbig; }
  const int bm = blockIdx.y * 128, bn = blockIdx.x * 128;
  gemm_core_async(A, B, 0, DD, DD, DD, bm, bn, As, Bs, acc);
  #pragma unroll
  for (int i = 0; i < 4; ++i)
    #pragma unroll
    for (int j = 0; j < 4; ++j) {
      const int col = bn + wn + j * 16 + (lane & 15);
      #pragma unroll
      for (int r = 0; r < 4; ++r) {
        const int row = bm + wm + i * 16 + (lane >> 4) * 4 + r;
        C[(size_t)row * DD + col] = __float2bfloat16(acc[i][j][r]);
      }
    }
}

// main GEMM [8192 x 6144 x 1024]: cols 0..1023 -> invtot/nxt (fp32);
// cols 1024+ -> int8 sign(out_z) + fused per-row S,Q (butterfly + atomics)
__global__ __launch_bounds__(256, 4)
void gemm_main(const bf16* __restrict__ A, const bf16* __restrict__ Bb,
               const float* __restrict__ biasall, const float* __restrict__ x,
               float* __restrict__ invtot, float* __restrict__ nxtf,
               signed char* __restrict__ sgn, float* __restrict__ Srow, float* __restrict__ Qrow) {
  GEMM_PROLOGUE
  const int bm = blockIdx.y * 128, bn = blockIdx.x * 128;
  gemm_core_async(A, Bb + (size_t)(bn >> 10) * MSZ, 0, DD, DD, DD, bm, bn & (DD - 1), As, Bs, acc);

  if (bn < DD) {
    #pragma unroll
    for (int i = 0; i < 4; ++i)
      #pragma unroll
      for (int j = 0; j < 4; ++j) {
        const int col = bn + wn + j * 16 + (lane & 15);
        const float bj = biasall[col];
        #pragma unroll
        for (int r = 0; r < 4; ++r) {
          const int row = bm + wm + i * 16 + (lane >> 4) * 4 + r;
          const float v = acc[i][j][r] + bj;
          const size_t idx = (size_t)row * DD + col;
          invtot[idx] = v;
          nxtf[idx] = x[idx] - v;
        }
      }
  } else {
    const int z = (bn >> 10) - 1;
    signed char* oz = sgn + (size_t)z * NR * DD;
    const int cbase = bn & (DD - 1);
    float sv[4][4] = {}, qv[4][4] = {};
    #pragma unroll
    for (int i = 0; i < 4; ++i)
      #pragma unroll
      for (int j = 0; j < 4; ++j) {
        const int colg = bn + wn + j * 16 + (lane & 15);
        const int cj = cbase + wn + j * 16 + (lane & 15);
        const float bj = biasall[colg];
        #pragma unroll
        for (int r = 0; r < 4; ++r) {
          const int row = bm + wm + i * 16 + (lane >> 4) * 4 + r;
          const float v = acc[i][j][r] + bj;
          oz[(size_t)row * DD + cj] = (signed char)((v > 0.f) - (v < 0.f));
          sv[i][r] += v;
          qv[i][r] += v * v;
        }
      }
    #pragma unroll
    for (int i = 0; i < 4; ++i)
      #pragma unroll
      for (int r = 0; r < 4; ++r) {
        float s = sv[i][r], q = qv[i][r];
        #pragma unroll
        for (int off = 1; off < 16; off <<= 1) { s += __shfl_xor(s, off); q += __shfl_xor(q, off); }
        if ((lane & 15) == 0) {
          const int row = bm + wm + i * 16 + (lane >> 4) * 4 + r;
          atomicAdd(&Srow[(size_t)z * NR + row], s);
          atomicAdd(&Qrow[(size_t)z * NR + row], q);
        }
      }
  }
}

// ---------------- loss ----------------

// Dtot[z][j] += sum_n |s[n+1,j]*Sp[n+1] - s[n,j]*Sp[n]|, Sp = S/(32*sqrt(Q))
#define LCR 64
__global__ void losscol3_kernel(const signed char* __restrict__ sgn, const float* __restrict__ Srow,
                                const float* __restrict__ Qrow, float* __restrict__ Dtot) {
  const int z = blockIdx.y;
  const int n0 = blockIdx.x * LCR;
  int nend = n0 + LCR; if (nend > NR - 1) nend = NR - 1;
  const signed char* base = sgn + (size_t)z * NR * DD + (size_t)threadIdx.x * 4;
  const float* S = Srow + (size_t)z * NR;
  const float* Q = Qrow + (size_t)z * NR;
  float d[4] = {0.f, 0.f, 0.f, 0.f};
  char4 s0 = *(const char4*)(base + (size_t)n0 * DD);
  float Sp0 = S[n0] / (32.f * sqrtf(Q[n0]));
  for (int n = n0 + 1; n <= nend; ++n) {
    char4 s1 = *(const char4*)(base + (size_t)n * DD);
    float Sp1 = S[n] / (32.f * sqrtf(Q[n]));
    d[0] += fabsf((float)s1.x * Sp1 - (float)s0.x * Sp0);
    d[1] += fabsf((float)s1.y * Sp1 - (float)s0.y * Sp0);
    d[2] += fabsf((float)s1.z * Sp1 - (float)s0.z * Sp0);
    d[3] += fabsf((float)s1.w * Sp1 - (float)s0.w * Sp0);
    s0 = s1; Sp0 = Sp1;
  }
  #pragma unroll
  for (int k = 0; k < 4; ++k) atomicAdd(&Dtot[z * DD + threadIdx.x * 4 + k], d[k]);
}

__global__ void writeloss_kernel(const float* __restrict__ Dtot, float* __restrict__ out) {
  int idx = blockIdx.x * 256 + threadIdx.x;
  int j = idx & (DD - 1);
  out[idx] = Dtot[j] + Dtot[DD + j] + Dtot[2 * DD + j] + Dtot[3 * DD + j] + Dtot[4 * DD + j];
}

// ---------------- launch ----------------

extern "C" void kernel_launch(void* const* d_in, const int* in_sizes, int n_in,
                              void* d_out, int out_size, void* d_ws, size_t ws_size,
                              hipStream_t stream) {
  const float* x      = (const float*)d_in[0];
  const float* fc1_W  = (const float*)d_in[1];
  const float* fc1_b  = (const float*)d_in[2];
  const float* fc2_W  = (const float*)d_in[3];
  const float* fc2_b  = (const float*)d_in[4];
  const float* comp_W = (const float*)d_in[5];
  const float* comp_b = (const float*)d_in[6];

  float* invtot  = (float*)d_out;
  float* nxtf    = invtot + (size_t)NR * DD;
  float* lossout = invtot + (size_t)2 * NR * DD;

  char* w = (char*)d_ws;
  auto alloc = [&](size_t bytes) { char* p = w; w += (bytes + 255) & ~(size_t)255; return p; };
  bf16* x_bf     = (bf16*)alloc((size_t)NR * DD * 2);          // 16 MB
  bf16* fc1T_bf  = (bf16*)alloc((size_t)DD * HH * 2);          // 8 MB
  bf16* fc2_bf   = (bf16*)alloc((size_t)DD * HH * 2);          // 8 MB
  bf16* compW_bf = (bf16*)alloc((size_t)NL * MSZ * 2);         // 10 MB
  bf16* M_bf     = (bf16*)alloc((size_t)MSZ * 2);              // 2 MB
  bf16* Mt_bf    = (bf16*)alloc((size_t)MSZ * 2);              // 2 MB
  bf16* Ttb      = (bf16*)alloc((size_t)4 * MSZ * 2);          // [Tt,T2t,T3t,T4t] 8 MB
  bf16* Pw       = (bf16*)alloc((size_t)4 * MSZ * 2);          // [T,T2,T3,T4] 8 MB
  bf16* S_bf     = (bf16*)alloc((size_t)MSZ * 2);              // 2 MB
  bf16* Gt       = (bf16*)alloc((size_t)4 * MSZ * 2);          // [G2t..G5t] 8 MB
  bf16* Bbig     = (bf16*)alloc((size_t)6 * MSZ * 2);          // 12 MB
  signed char* sgn = (signed char*)alloc((size_t)NL * NR * DD); // 40 MB
  float* cvec    = (float*)alloc(DD * 4);
  float* ebuf    = (float*)alloc((size_t)4 * DD * 4);
  float* biasall = (float*)alloc((size_t)6 * DD * 4);
  float* stats   = (float*)alloc((size_t)(NL * DD + 2 * NL * NR) * 4);
  float* Dtot = stats;
  float* Srow = stats + NL * DD;
  float* Qrow = Srow + (size_t)NL * NR;
  const int nstats = NL * DD + 2 * NL * NR;
  // split-K fp32 partials (16 MB) alias sgn: consumed by mbuild before gemm_main writes sgn
  float* Cp = (float*)sgn;
  (void)ws_size; (void)in_sizes; (void)n_in; (void)out_size;

  // 1. fused prep (all cvts + transpose + cvec + zero)
  prep_kernel<<<4608, 256, 0, stream>>>(x, fc2_W, comp_W, fc1_W, fc1_b, fc2_b,
                                        x_bf, fc2_bf, compW_bf, fc1T_bf, cvec, stats, nstats);
  // 2. M = fc1^T fc2^T (K=4096) via split-K(4)
  gemm_splitk<<<dim3(8, 8, 4), 256, 0, stream>>>(fc1T_bf, fc2_bf, Cp);
  // 3. combine -> M/Mt/T/Tt
  mbuild_kernel<<<dim3(16, 16), 256, 0, stream>>>(Cp, M_bf, Mt_bf, Pw, Ttb);
  // 4. batch6: G1..G5 (G1 -> Bbig+MSZ directly) + T2 dual
  gemm_pre1<<<dim3(8, 8, 6), 256, 0, stream>>>(compW_bf, M_bf, Pw, Ttb,
                                               Bbig + MSZ, Gt, Pw + MSZ, Ttb + MSZ);
  // 5. batch2 dual: T3, T4 (+ transposed)
  gemm_pre2<<<dim3(8, 8, 2), 256, 0, stream>>>(Pw + MSZ, Ttb, Pw, Ttb);
  // 6. S = I+T+T2+T3+T4
  sbuild_kernel<<<MSZ / 256, 256, 0, stream>>>(Pw, S_bf);
  // 7. e2..e5 = c.T^{1..4} in one batch
  vecmat4_kernel<<<dim3(DD, 4), 256, 0, stream>>>(cvec, Ttb, ebuf);
  // 8. bias vectors
  biasall_kernel<<<dim3(DD, 6), 256, 0, stream>>>(cvec, ebuf, compW_bf, comp_b, biasall);
  // 9. final batch: Bout2..5^T + (S*M)^T
  gemm_final<<<dim3(8, 8, 5), 256, 0, stream>>>(Gt, Pw, Mt_bf, S_bf, Bbig);
  // 10. main GEMM
  gemm_main<<<dim3(6 * DD / 128, NR / 128), 256, 0, stream>>>(
      x_bf, Bbig, biasall, x, invtot, nxtf, sgn, Srow, Qrow);
  // 11. loss column reduction
  losscol3_kernel<<<dim3(NR / LCR, NL), 256, 0, stream>>>(sgn, Srow, Qrow, Dtot);
  // 12. rank-1 broadcast
  writeloss_kernel<<<MSZ / 256, 256, 0, stream>>>(Dtot, lossout);
}